// Round 20
// baseline (34.846 us; speedup 1.0000x reference)
//
#include <hip/hip_runtime.h>
#include <stdint.h>

// Problem constants
#define N_ANCHOR 2048
#define DIM 128
#define NEG_PER 15
#define NZ 32768                    // 2048*16 candidate rows
#define INV_TEMP 3.3333333333333335f
#define LN2 0.6931471805599453f
#define TOTAL_ELEMS 67108864.0f
#define PRE (INV_TEMP * 0.5f)       // anchor prescale: dot output y = l/2

#define NPREP 1088                  // 64 anchor tiles + 1024 z tiles
#define NGRAM 68                    // 4 A-blocks (K=512) + 64 Z-blocks (K=512)
#define NTRACE 32

using bf16x8 = __attribute__((ext_vector_type(8))) __bf16;
using f32x16 = __attribute__((ext_vector_type(16))) float;
using u16x8  = __attribute__((ext_vector_type(8))) unsigned short;

// ---------- helpers ----------
static __device__ __forceinline__ unsigned short f2bf(float f) {
  union { float f; unsigned u; } v; v.f = f;
  unsigned r = v.u + 0x7FFF + ((v.u >> 16) & 1);   // round-to-nearest-even
  return (unsigned short)(r >> 16);
}
static __device__ __forceinline__ float bf2f(unsigned short u) {
  union { unsigned u; float f; } v; v.u = ((unsigned)u) << 16;
  return v.f;
}
static __device__ __forceinline__ void gload_lds16(const void* g, void* l) {
  __builtin_amdgcn_global_load_lds(
      (const __attribute__((address_space(1))) void*)g,
      (__attribute__((address_space(3))) void*)l, 16, 0, 0);
}

// ---------- kernel 1: prep ------------------------------------------------
// Normalize 32 rows -> LDS; write GRAM-frag-major global (both aG and zG):
// 256-cand chunk layout [ks 0..15][D 0..3][l 0..63][j 0..7]:
//   value = zdm[D*32+(l&31)][ks*16+(l>>5)*8+j]  (dim-major)
// A block covers 2 ks-groups of its chunk. Plus per-block colsum partials
// Scp[T][128] and (z blocks) fused dpart (R18-verified).
__global__ __launch_bounds__(256) void prep_kernel(
    const float* __restrict__ anchor, const float* __restrict__ pos,
    const float* __restrict__ neg, unsigned short* __restrict__ aG,
    unsigned short* __restrict__ zG, float* __restrict__ dpart,
    float* __restrict__ Scp) {
  const int T = blockIdx.x, t = threadIdx.x;
  __shared__ unsigned short lz[32 * 132];
  __shared__ float csb[256];
  __shared__ float wna[4], wdd[4];
  const int r = t >> 3, q = t & 7;       // 8 threads per row, 16 dims each
  const float* src;
  float pre;
  if (T < 64) {
    src = anchor + (size_t)(T * 32 + r) * DIM;
    pre = PRE;
  } else {
    int c = (T - 64) * 32 + r;
    int j = c >> 4, k = c & 15;
    src = (k == 0) ? (pos + (size_t)j * DIM)
                   : (neg + (size_t)(j * NEG_PER + k - 1) * DIM);
    pre = 1.0f;
  }
  float4 v[4];
  #pragma unroll
  for (int m = 0; m < 4; ++m) v[m] = *(const float4*)(src + q * 16 + m * 4);
  float s = 0.f;
  #pragma unroll
  for (int m = 0; m < 4; ++m)
    s += v[m].x * v[m].x + v[m].y * v[m].y + v[m].z * v[m].z + v[m].w * v[m].w;
  s += __shfl_xor(s, 1); s += __shfl_xor(s, 2); s += __shfl_xor(s, 4);
  float sc = pre / fmaxf(sqrtf(s), 1e-12f);
  #pragma unroll
  for (int m = 0; m < 4; ++m) {
    ushort4 w;
    w.x = f2bf(v[m].x * sc); w.y = f2bf(v[m].y * sc);
    w.z = f2bf(v[m].z * sc); w.w = f2bf(v[m].w * sc);
    *(ushort4*)(lz + r * 132 + q * 16 + m * 4) = w;
  }
  __syncthreads();

  // Gram-frag writeout: 512 slots of 16B, 2 passes (coalesced stores)
  const int Tl = (T < 64) ? T : T - 64;
  unsigned short* gdst = ((T < 64) ? aG : zG) +
                         (size_t)(Tl >> 3) * 32768 + (size_t)(Tl & 7) * 4096;
  #pragma unroll
  for (int p2 = 0; p2 < 2; ++p2) {
    int sp   = p2 * 256 + t;
    int addr = ((sp >> 8) << 11) + (((sp >> 6) & 3) << 9) + ((sp & 63) << 3);
    int crow = ((sp >> 8) << 4) + (((sp >> 5) & 1) << 3);  // cand offset base
    int dim  = (((sp >> 6) & 3) << 5) + (sp & 31);
    u16x8 w;
    #pragma unroll
    for (int j = 0; j < 8; ++j) w[j] = lz[(crow + j) * 132 + dim];
    *(u16x8*)(gdst + addr) = w;
  }

  // colsum partial (both block kinds): Scp[T][d] = sum of 32 rows at dim d
  {
    int d = t & 127, h = t >> 7;
    float cs = 0.f;
    #pragma unroll
    for (int rr = 0; rr < 16; ++rr) cs += bf2f(lz[(h * 16 + rr) * 132 + d]);
    csb[t] = cs;
  }
  __syncthreads();
  if (t < 128) Scp[(size_t)T * 128 + t] = csb[t] + csb[t + 128];

  if (T >= 64) {                         // ---- fused diagonal (R18) ----
    const int a = t >> 7;                // anchor sub-group 0/1
    const int d = t & 127;
    float zs = 0.f;
    #pragma unroll
    for (int rr = 0; rr < 16; ++rr)
      zs += bf2f(lz[(a * 16 + rr) * 132 + d]);
    const int j = (T - 64) * 2 + a;
    float av = anchor[(size_t)j * DIM + d];
    float pna = av * av, pdd = av * zs;
    #pragma unroll
    for (int o = 32; o >= 1; o >>= 1) {
      pna += __shfl_xor(pna, o);
      pdd += __shfl_xor(pdd, o);
    }
    if ((t & 63) == 0) { wna[t >> 6] = pna; wdd[t >> 6] = pdd; }
    __syncthreads();
    if ((t & 127) == 0) {
      int w0 = t >> 6;                   // 0 or 2
      float na = wna[w0] + wna[w0 + 1];
      float dd = wdd[w0] + wdd[w0 + 1];
      dpart[j] = PRE * dd / fmaxf(sqrtf(na), 1e-12f);
    }
  }
}

// ---------- kernel 2: partial Gram matrices -------------------------------
// Block b: A (b<4, K=512 of aG) or Z (b>=4, K=512 of zG). Gram symmetry:
// A-frag(D) == B-frag(D) == 16B at ch[ks*2048 + D*512 + lane*8] (frag
// formulas HW-verified by R7-R19's passing GEMMs). Output written in a
// BLIND bijective lane-major layout (fully coalesced); trace-dot is
// permutation-invariant since A- and Z-partials share the mapping.
__global__ __launch_bounds__(256) void gram_kernel(
    const unsigned short* __restrict__ aG,
    const unsigned short* __restrict__ zG, float* __restrict__ GP) {
  __shared__ __align__(16) unsigned short ch[2][32768];   // 2 x 64 KB
  const int b = blockIdx.x, t = threadIdx.x;
  const int wave = t >> 6, lane = t & 63;
  const unsigned short* src =
      (b < 4) ? (aG + (size_t)b * 65536) : (zG + (size_t)(b - 4) * 65536);

#define STG(buf, c)                                                        \
  {                                                                        \
    const unsigned short* s_ = src + (size_t)(c) * 32768 + t * 8;          \
    _Pragma("unroll")                                                      \
    for (int it = 0; it < 16; ++it)                                        \
      gload_lds16(s_ + it * 2048, (buf) + (it * 256 + wave * 64) * 8);     \
  }

  STG(ch[0], 0)
  STG(ch[1], 1)

  f32x16 acc0 = 0.0f, acc1 = 0.0f, acc2 = 0.0f, acc3 = 0.0f;

#define CMP(buf)                                                           \
  _Pragma("unroll")                                                        \
  for (int ks = 0; ks < 16; ++ks) {                                        \
    const unsigned short* p_ = (buf) + ks * 2048 + lane * 8;               \
    bf16x8 fA = *(const bf16x8*)(p_ + wave * 512);                         \
    bf16x8 f0 = *(const bf16x8*)(p_);                                      \
    bf16x8 f1 = *(const bf16x8*)(p_ + 512);                                \
    bf16x8 f2 = *(const bf16x8*)(p_ + 1024);                               \
    bf16x8 f3 = *(const bf16x8*)(p_ + 1536);                               \
    acc0 = __builtin_amdgcn_mfma_f32_32x32x16_bf16(fA, f0, acc0, 0, 0, 0); \
    acc1 = __builtin_amdgcn_mfma_f32_32x32x16_bf16(fA, f1, acc1, 0, 0, 0); \
    acc2 = __builtin_amdgcn_mfma_f32_32x32x16_bf16(fA, f2, acc2, 0, 0, 0); \
    acc3 = __builtin_amdgcn_mfma_f32_32x32x16_bf16(fA, f3, acc3, 0, 0, 0); \
  }

  asm volatile("s_waitcnt vmcnt(16)" ::: "memory");
  __builtin_amdgcn_s_barrier();
  CMP(ch[0])
  asm volatile("s_waitcnt vmcnt(0)" ::: "memory");
  __builtin_amdgcn_s_barrier();
  CMP(ch[1])

  // blind coalesced writeout: addr = b*16384 + wave*4096 + dc*1024 + r*256
  //                                + lane*4  (bijection over 16384)
  float* gp = GP + (size_t)b * 16384 + wave * 4096 + lane * 4;
  #pragma unroll
  for (int r = 0; r < 4; ++r) {
    float4 v0 = {acc0[r * 4], acc0[r * 4 + 1], acc0[r * 4 + 2], acc0[r * 4 + 3]};
    float4 v1 = {acc1[r * 4], acc1[r * 4 + 1], acc1[r * 4 + 2], acc1[r * 4 + 3]};
    float4 v2 = {acc2[r * 4], acc2[r * 4 + 1], acc2[r * 4 + 2], acc2[r * 4 + 3]};
    float4 v3 = {acc3[r * 4], acc3[r * 4 + 1], acc3[r * 4 + 2], acc3[r * 4 + 3]};
    *(float4*)(gp + 0 * 1024 + r * 256) = v0;
    *(float4*)(gp + 1 * 1024 + r * 256) = v1;
    *(float4*)(gp + 2 * 1024 + r * 256) = v2;
    *(float4*)(gp + 3 * 1024 + r * 256) = v3;
  }
}

// ---------- kernel 3: trace-dot + colsum-dot partials ---------------------
// tp[g] = 0.5 * Sum_{p in slice} (Sum_A GP)(Sum_Z GP)
//       + Sum_{d in slice} sa[d]*sz[d]
__global__ __launch_bounds__(256) void trace_kernel(
    const float* __restrict__ GP, const float* __restrict__ Scp,
    float* __restrict__ tp) {
  __shared__ float red[4];
  const int g = blockIdx.x, t = threadIdx.x;
  const int wave = t >> 6, lane = t & 63;
  float s = 0.f;
  #pragma unroll
  for (int it = 0; it < 2; ++it) {       // 512 positions per block
    int p = g * 512 + it * 256 + t;
    float ga = 0.f, gz = 0.f;
    #pragma unroll
    for (int b = 0; b < 4; ++b) ga += GP[(size_t)b * 16384 + p];
    #pragma unroll 8
    for (int b = 4; b < NGRAM; ++b) gz += GP[(size_t)b * 16384 + p];
    s += 0.5f * ga * gz;
  }
  {                                      // dim d = g*4 + wave
    int d = g * 4 + wave;
    float sa = Scp[(size_t)lane * 128 + d];             // 64 A partials
    float sz = 0.f;
    #pragma unroll
    for (int k = 0; k < 16; ++k)                        // 1024 Z partials
      sz += Scp[(size_t)(64 + lane + k * 64) * 128 + d];
    #pragma unroll
    for (int o = 32; o >= 1; o >>= 1) {
      sa += __shfl_xor(sa, o);
      sz += __shfl_xor(sz, o);
    }
    if (lane == 0) s += sa * sz;
  }
  #pragma unroll
  for (int o = 32; o >= 1; o >>= 1) s += __shfl_xor(s, o);
  if (lane == 0) red[wave] = s;
  __syncthreads();
  if (t == 0) tp[g] = (red[0] + red[1]) + (red[2] + red[3]);
}

// ---------- kernel 4: final -----------------------------------------------
// out = LN2 + (Sum tp - 2*Sum dpart) / N
__global__ __launch_bounds__(256) void final_kernel(
    const float* __restrict__ tp, const float* __restrict__ dpart,
    float* __restrict__ out) {
  __shared__ float red[4];
  const int t = threadIdx.x;
  float s = (t < NTRACE) ? tp[t] : 0.f;
  #pragma unroll
  for (int i = 0; i < N_ANCHOR / 256; ++i) s -= 2.0f * dpart[i * 256 + t];
  #pragma unroll
  for (int o = 32; o >= 1; o >>= 1) s += __shfl_xor(s, o);
  if ((t & 63) == 0) red[t >> 6] = s;
  __syncthreads();
  if (t == 0)
    out[0] = LN2 +
             ((red[0] + red[1]) + (red[2] + red[3])) * (1.0f / TOTAL_ELEMS);
}

extern "C" void kernel_launch(void* const* d_in, const int* in_sizes, int n_in,
                              void* d_out, int out_size, void* d_ws, size_t ws_size,
                              hipStream_t stream) {
  const float* anchor = (const float*)d_in[0];
  const float* pos    = (const float*)d_in[1];
  const float* neg    = (const float*)d_in[2];
  char* ws = (char*)d_ws;
  unsigned short* aG = (unsigned short*)ws;                      // 512 KB
  unsigned short* zG = (unsigned short*)(ws + 524288);           // 8 MB
  float* GP    = (float*)(ws + 8912896);                         // 4.36 MB
  float* Scp   = (float*)(ws + 13369344);                        // 557 KB
  float* dpart = (float*)(ws + 13926400);                        // 8 KB
  float* tp    = (float*)(ws + 13934592);                        // 128 B

  prep_kernel<<<dim3(NPREP), dim3(256), 0, stream>>>(anchor, pos, neg,
                                                     aG, zG, dpart, Scp);
  gram_kernel<<<dim3(NGRAM), dim3(256), 0, stream>>>(aG, zG, GP);
  trace_kernel<<<dim3(NTRACE), dim3(256), 0, stream>>>(GP, Scp, tp);
  final_kernel<<<dim3(1), dim3(256), 0, stream>>>(tp, dpart, (float*)d_out);
}